// Round 8
// baseline (163.538 us; speedup 1.0000x reference)
//
#include <hip/hip_runtime.h>

#define TT 2048
#define DD 1024
#define HH 16
#define DH 64
#define QKV_N 3072
#define QKW 2048  // qk buffer width (Q cols 0..1023, K cols 1024..2047)

typedef __attribute__((ext_vector_type(8))) short bf16x8;
typedef __attribute__((ext_vector_type(4))) short short4v;
typedef __attribute__((ext_vector_type(4))) float f32x4;

__device__ inline short f2bf(float f) {
    union { float f; unsigned u; } v; v.f = f;
    unsigned r = v.u + 0x7fff + ((v.u >> 16) & 1);  // RNE
    return (short)(r >> 16);
}

__device__ inline f32x4 mfma16(bf16x8 a, bf16x8 b, f32x4 c) {
    return __builtin_amdgcn_mfma_f32_16x16x32_bf16(a, b, c, 0, 0, 0);
}

__device__ __forceinline__ void gload16(const void* g, void* l) {
    __builtin_amdgcn_global_load_lds(
        (const __attribute__((address_space(1))) unsigned int*)g,
        (__attribute__((address_space(3))) unsigned int*)l, 16, 0, 0);
}

// ---------------------------------------------------------------------------
// 1. prep: x cast, weight/state transposes, new_state init, scan
// ---------------------------------------------------------------------------
__device__ void transpose_tile(const float* __restrict__ in, short* __restrict__ out,
                               int R, int C, int r0, int c0, float (*tile)[65]) {
    int tid = threadIdx.x;
#pragma unroll
    for (int p = 0; p < 4; ++p) {
        int ch = tid + p * 256;
        int r = ch >> 4, c4 = (ch & 15) * 4;
        float4 v = *(const float4*)&in[(size_t)(r0 + r) * C + c0 + c4];
        tile[r][c4] = v.x; tile[r][c4 + 1] = v.y; tile[r][c4 + 2] = v.z; tile[r][c4 + 3] = v.w;
    }
    __syncthreads();
#pragma unroll
    for (int p = 0; p < 2; ++p) {
        int ch = tid + p * 256;
        int c = ch >> 3, r8 = (ch & 7) * 8;
        short tmp[8];
#pragma unroll
        for (int i = 0; i < 8; ++i) tmp[i] = f2bf(tile[r8 + i][c]);
        *(float4*)&out[(size_t)(c0 + c) * R + r0 + r8] = *(float4*)tmp;
    }
}

__global__ __launch_bounds__(256) void prep_kernel(const float* __restrict__ x,
                                                   const float* __restrict__ w_qkv,
                                                   const float* __restrict__ w_out,
                                                   const float* __restrict__ state,
                                                   const int* __restrict__ done,
                                                   short* __restrict__ x_bf,
                                                   short* __restrict__ wqT,
                                                   short* __restrict__ woT,
                                                   short* __restrict__ stT,
                                                   float* __restrict__ stout,
                                                   int* __restrict__ seg,
                                                   int* __restrict__ totalp,
                                                   int* __restrict__ aux) {
    __shared__ float tile[64][65];
    __shared__ int scanbuf[2048 + 512 + 1];
    int b = blockIdx.x;
    int tid = threadIdx.x;
    if (b < 1024) {
        int i = (b * 256 + tid) * 8;
        float4 a = *(const float4*)&x[i];
        float4 c = *(const float4*)&x[i + 4];
        short tmp[8] = {f2bf(a.x), f2bf(a.y), f2bf(a.z), f2bf(a.w),
                        f2bf(c.x), f2bf(c.y), f2bf(c.z), f2bf(c.w)};
        *(float4*)&x_bf[i] = *(float4*)tmp;
    } else if (b < 1792) {
        int bb = b - 1024;
        transpose_tile(w_qkv, wqT, DD, QKV_N, (bb & 15) * 64, (bb >> 4) * 64, tile);
    } else if (b < 2048) {
        int bb = b - 1792;
        transpose_tile(w_out, woT, DD, DD, (bb & 15) * 64, (bb >> 4) * 64, tile);
    } else if (b < 2064) {
        int h = b - 2048;
        transpose_tile(state + (size_t)h * 4096, stT + (size_t)h * 4096, DH, DH, 0, 0, tile);
    } else if (b < 2128) {
        __shared__ int anyf;
        if (tid == 0) anyf = 0;
        __syncthreads();
        int acc = 0;
#pragma unroll
        for (int i = 0; i < 8; ++i) acc |= done[tid * 8 + i];
        if (acc) anyf = 1;
        __syncthreads();
        int f = ((b - 2064) * 256 + tid) * 4;
        float4 v = anyf ? make_float4(0.f, 0.f, 0.f, 0.f) : *(const float4*)&state[f];
        *(float4*)&stout[f] = v;
    } else {
        int* segl = scanbuf;
        int* part = scanbuf + 2048;
        int* excl = scanbuf + 2304;
        int base = tid * 8;
        int local[8];
        int run = 0;
#pragma unroll
        for (int i = 0; i < 8; ++i) { run += (done[base + i] != 0) ? 1 : 0; local[i] = run; }
        part[tid] = run;
        __syncthreads();
        if (tid < 64) {
            int p4[4];
#pragma unroll
            for (int i = 0; i < 4; ++i) p4[i] = part[tid * 4 + i];
            int s = p4[0] + p4[1] + p4[2] + p4[3];
            int v = s;
#pragma unroll
            for (int off = 1; off < 64; off <<= 1) {
                int u = __shfl_up(v, off);
                if (tid >= off) v += u;
            }
            int ex = v - s;
#pragma unroll
            for (int i = 0; i < 4; ++i) { excl[tid * 4 + i] = ex; ex += p4[i]; }
            if (tid == 63) { totalp[0] = v; scanbuf[2560] = v; }
        }
        __syncthreads();
        int off = excl[tid];
#pragma unroll
        for (int i = 0; i < 8; ++i) {
            int sv = off + local[i];
            seg[base + i] = sv;
            segl[base + i] = sv;
        }
        __syncthreads();
        if (tid < 33) {
            int target = (tid < 32) ? segl[tid * 64] : scanbuf[2560];
            int lo = 0, hi = 2047;
            while (lo < hi) { int mid = (lo + hi) >> 1; if (segl[mid] >= target) hi = mid; else lo = mid + 1; }
            aux[tid] = lo >> 6;
        }
    }
}

// ---------------------------------------------------------------------------
// 2. QKV GEMM (m97 pattern): cols <2048 -> qk natural; cols >=2048 -> vt[h][e][t]
// ---------------------------------------------------------------------------
__global__ __launch_bounds__(256) void gemm_qkv(const short* __restrict__ A,
                                                const short* __restrict__ BT,
                                                const float* __restrict__ bias,
                                                short* __restrict__ qk,
                                                short* __restrict__ vt) {
    __shared__ __align__(16) short As[128 * 32];
    __shared__ __align__(16) short Bs[128 * 32];
    const int K = DD;
    int tid = threadIdx.x;
    int wave = tid >> 6, lane = tid & 63;
    int quad = lane >> 4, l15 = lane & 15;
    int m0 = blockIdx.x * 128, n0 = blockIdx.y * 128;
    int wr = (wave >> 1) * 64, wc = (wave & 1) * 64;

    int srow = wave * 16 + (lane >> 2);
    int scol = (lane & 3) * 8;
    const short* Ag = A + (size_t)(m0 + srow) * K + scol;
    const short* Bg = BT + (size_t)(n0 + srow) * K + scol;
    short* As0 = &As[(wave * 16) * 32];
    short* As1 = &As[(64 + wave * 16) * 32];
    short* Bs0 = &Bs[(wave * 16) * 32];
    short* Bs1 = &Bs[(64 + wave * 16) * 32];

    f32x4 acc[4][4] = {};
    for (int k0 = 0; k0 < K; k0 += 32) {
        __syncthreads();
        gload16(Ag + k0, As0);
        gload16(Ag + (size_t)64 * K + k0, As1);
        gload16(Bg + k0, Bs0);
        gload16(Bg + (size_t)64 * K + k0, Bs1);
        __syncthreads();
        bf16x8 af[4], bfr[4];
#pragma unroll
        for (int i = 0; i < 4; ++i) {
            af[i]  = *(const bf16x8*)&As[(wr + i * 16 + l15) * 32 + quad * 8];
            bfr[i] = *(const bf16x8*)&Bs[(wc + i * 16 + l15) * 32 + quad * 8];
        }
#pragma unroll
        for (int i = 0; i < 4; ++i)
#pragma unroll
            for (int j = 0; j < 4; ++j)
                acc[i][j] = mfma16(af[i], bfr[j], acc[i][j]);
    }

    if (n0 < 2048) {
#pragma unroll
        for (int i = 0; i < 4; ++i)
#pragma unroll
            for (int j = 0; j < 4; ++j)
#pragma unroll
                for (int r = 0; r < 4; ++r) {
                    int row = m0 + wr + i * 16 + quad * 4 + r;
                    int col = n0 + wc + j * 16 + l15;
                    qk[(size_t)row * QKW + col] = f2bf(acc[i][j][r] + bias[col]);
                }
    } else {
#pragma unroll
        for (int j = 0; j < 4; ++j) {
            int col = n0 + wc + j * 16 + l15;
            float bv = bias[col];
            int eg = col - 2048;
            int hh = eg >> 6, e = eg & 63;
#pragma unroll
            for (int i = 0; i < 4; ++i) {
                int tb = m0 + wr + i * 16 + quad * 4;
                short4v pk;
#pragma unroll
                for (int r = 0; r < 4; ++r) pk[r] = f2bf(acc[i][j][r] + bv);
                *(short4v*)&vt[(size_t)hh * (DH * TT) + (size_t)e * TT + tb] = pk;
            }
        }
    }
}

// ---------------------------------------------------------------------------
// 3. attention — no chunking, double-buffered staging, 1 barrier/iter.
//    grid (H, 16 t-blocks of 128, z: 0=attn, 1=state). 4 waves x 32 t-rows.
//    QK computed as S^T (D[s][t]) -> packed b64 masked stores; PV/state
//    computed as out^T (D[e][t]) -> packed b64 epilogue.
// ---------------------------------------------------------------------------
__global__ __launch_bounds__(256) void attn_mfma(const short* __restrict__ qk,
                                                 const short* __restrict__ vt,
                                                 const short* __restrict__ stT,
                                                 const int* __restrict__ seg,
                                                 const int* __restrict__ totalp,
                                                 const int* __restrict__ aux,
                                                 short* __restrict__ outb,
                                                 float* __restrict__ nsout) {
    __shared__ __align__(16) short Qh[2][128 * 32];     // [d-half][t][32]
    __shared__ __align__(16) short Kh[2][2][64 * 32];   // [buf][d-half][s][32]
    __shared__ __align__(16) short Vh[2][2][64 * 32];   // [buf][s-half][e][32]
    __shared__ __align__(16) short Ss[128 * 72];        // [t][s], stride 72

    int h = blockIdx.x, tb = blockIdx.y;
    int t0 = tb * 128;
    int tid = threadIdx.x, wave = tid >> 6, lane = tid & 63;
    int quad = lane >> 4, l15 = lane & 15;
    int myt = wave * 32;
    const short* vbase = vt + (size_t)h * (DH * TT);

    if (blockIdx.z == 1) {
        // ---- state path: chunks ct = 2tb, 2tb+1; atomicAdd onto nsout
        int total = totalp[0];
        int myd = wave * 16;
        short* KhS0 = Kh[0][0];
        short* KhS1 = Kh[0][1];
#pragma unroll
        for (int cc = 0; cc < 2; ++cc) {
            int ct = tb * 2 + cc;
            if (ct < aux[32]) continue;
            int t0c = ct * 64;
            bool keep = (seg[t0c + lane] == total);
            const short* src = qk + (size_t)(t0c + lane) * QKW + 1024 + h * DH + myd;
            union { float4 f; short s[8]; } u0, u1;
            u0.f = keep ? *(const float4*)src : make_float4(0.f, 0.f, 0.f, 0.f);
            u1.f = keep ? *(const float4*)(src + 8) : make_float4(0.f, 0.f, 0.f, 0.f);
            short* dst = (lane < 32) ? &KhS0[lane] : &KhS1[lane - 32];
#pragma unroll
            for (int i = 0; i < 8; ++i) {
                dst[(myd + i) * 32] = u0.s[i];
                dst[(myd + 8 + i) * 32] = u1.s[i];
            }
            bf16x8 a0 = *(const bf16x8*)&KhS0[(myd + l15) * 32 + quad * 8];
            bf16x8 a1 = *(const bf16x8*)&KhS1[(myd + l15) * 32 + quad * 8];
            f32x4 acc2[4] = {};
#pragma unroll
            for (int j = 0; j < 4; ++j) {
                const short* vrow = vbase + (size_t)(j * 16 + l15) * TT + t0c + quad * 8;
                bf16x8 b0 = *(const bf16x8*)vrow;
                bf16x8 b1 = *(const bf16x8*)(vrow + 32);
                acc2[j] = mfma16(a0, b0, acc2[j]);
                acc2[j] = mfma16(a1, b1, acc2[j]);
            }
            float* oh = nsout + (size_t)h * 4096;
#pragma unroll
            for (int j = 0; j < 4; ++j)
#pragma unroll
                for (int r = 0; r < 4; ++r)
                    atomicAdd(&oh[(myd + quad * 4 + r) * DH + j * 16 + l15], acc2[j][r]);
        }
        return;
    }

    int st0 = aux[2 * tb];
    int st_hi = 2 * tb + 1;

    int srow = wave * 16 + (lane >> 2);
    int chunk = (lane & 3);
    const short* kg = qk + 1024 + h * DH;

    // ---- stage Q block (wave-private rows) + first K/V tiles
    {
        int sr = (lane >> 2);
#pragma unroll
        for (int h2 = 0; h2 < 2; ++h2)
#pragma unroll
            for (int q = 0; q < 2; ++q)
                gload16(qk + (size_t)(t0 + myt + q * 16 + sr) * QKW + h * DH + h2 * 32 + chunk * 8,
                        &Qh[h2][(myt + q * 16) * 32]);
        int s0 = st0 * 64;
        gload16(kg + (size_t)(s0 + srow) * QKW + chunk * 8,      &Kh[0][0][(wave * 16) * 32]);
        gload16(kg + (size_t)(s0 + srow) * QKW + 32 + chunk * 8, &Kh[0][1][(wave * 16) * 32]);
        gload16(vbase + (size_t)srow * TT + s0 + chunk * 8,      &Vh[0][0][(wave * 16) * 32]);
        gload16(vbase + (size_t)srow * TT + s0 + 32 + chunk * 8, &Vh[0][1][(wave * 16) * 32]);
    }
    __syncthreads();

    bf16x8 af[2][2];
#pragma unroll
    for (int i = 0; i < 2; ++i)
#pragma unroll
        for (int h2 = 0; h2 < 2; ++h2)
            af[i][h2] = *(const bf16x8*)&Qh[h2][(myt + i * 16 + l15) * 32 + quad * 8];

    int seg_lane[2], t_val[2];
#pragma unroll
    for (int i = 0; i < 2; ++i) {
        t_val[i] = t0 + myt + i * 16 + l15;
        seg_lane[i] = seg[t_val[i]];
    }

    f32x4 acc2[4][2] = {};  // out^T: [e-group j][t-group i], e=j*16+quad*4+r, t=myt+i*16+l15
    if (seg[t0] == 0) {
        const short* sb = stT + (size_t)h * 4096;  // [e][d]
#pragma unroll
        for (int j = 0; j < 4; ++j)
#pragma unroll
            for (int h2 = 0; h2 < 2; ++h2) {
                bf16x8 a = *(const bf16x8*)(sb + (j * 16 + l15) * 64 + h2 * 32 + quad * 8);
#pragma unroll
                for (int i = 0; i < 2; ++i)
                    acc2[j][i] = mfma16(a, af[i][h2], acc2[j][i]);
            }
#pragma unroll
        for (int i = 0; i < 2; ++i)
            if (seg_lane[i] != 0)
#pragma unroll
                for (int j = 0; j < 4; ++j)
#pragma unroll
                    for (int r = 0; r < 4; ++r) acc2[j][i][r] = 0.f;
    }

    int p = 0;
    for (int st = st0; st <= st_hi; ++st, p ^= 1) {
        if (st != st0) __syncthreads();  // drains prev staging; frees other buf
        if (st + 1 <= st_hi) {           // prefetch next tile into other buffer
            int s1 = (st + 1) * 64;
            gload16(kg + (size_t)(s1 + srow) * QKW + chunk * 8,      &Kh[p ^ 1][0][(wave * 16) * 32]);
            gload16(kg + (size_t)(s1 + srow) * QKW + 32 + chunk * 8, &Kh[p ^ 1][1][(wave * 16) * 32]);
            gload16(vbase + (size_t)srow * TT + s1 + chunk * 8,      &Vh[p ^ 1][0][(wave * 16) * 32]);
            gload16(vbase + (size_t)srow * TT + s1 + 32 + chunk * 8, &Vh[p ^ 1][1][(wave * 16) * 32]);
        }
        int s0 = st * 64;

        // S^T = K Q^T : D[s][t], s=j*16+quad*4+r, t=myt+i*16+l15
        f32x4 sacc[2][4] = {};
#pragma unroll
        for (int j = 0; j < 4; ++j)
#pragma unroll
            for (int h2 = 0; h2 < 2; ++h2) {
                bf16x8 kb = *(const bf16x8*)&Kh[p][h2][(j * 16 + l15) * 32 + quad * 8];
#pragma unroll
                for (int i = 0; i < 2; ++i)
                    sacc[i][j] = mfma16(kb, af[i][h2], sacc[i][j]);
            }
        // mask + packed b64 stores into Ss[t][s] (wave-private rows)
        int4 seg4[4];
#pragma unroll
        for (int j = 0; j < 4; ++j)
            seg4[j] = *(const int4*)&seg[s0 + j * 16 + quad * 4];
#pragma unroll
        for (int i = 0; i < 2; ++i)
#pragma unroll
            for (int j = 0; j < 4; ++j) {
                short4v pk;
#pragma unroll
                for (int r = 0; r < 4; ++r) {
                    int s_val = s0 + j * 16 + quad * 4 + r;
                    int sv = (r == 0) ? seg4[j].x : (r == 1) ? seg4[j].y : (r == 2) ? seg4[j].z : seg4[j].w;
                    bool ok = (sv == seg_lane[i]) && (s_val <= t_val[i]);
                    pk[r] = ok ? f2bf(sacc[i][j][r]) : (short)0;
                }
                *(short4v*)&Ss[(myt + i * 16 + l15) * 72 + j * 16 + quad * 4] = pk;
            }
        // out^T += V^T S^T : A=Vh rows (e), B=Ss rows (t)
        bf16x8 sf[2][2];
#pragma unroll
        for (int i = 0; i < 2; ++i)
#pragma unroll
            for (int h2 = 0; h2 < 2; ++h2)
                sf[i][h2] = *(const bf16x8*)&Ss[(myt + i * 16 + l15) * 72 + h2 * 32 + quad * 8];
#pragma unroll
        for (int j = 0; j < 4; ++j)
#pragma unroll
            for (int h2 = 0; h2 < 2; ++h2) {
                bf16x8 vb = *(const bf16x8*)&Vh[p][h2][(j * 16 + l15) * 32 + quad * 8];
#pragma unroll
                for (int i = 0; i < 2; ++i)
                    acc2[j][i] = mfma16(vb, sf[i][h2], acc2[j][i]);
            }
    }

    // epilogue: packed b64 stores, e=j*16+quad*4..+3 contiguous
#pragma unroll
    for (int i = 0; i < 2; ++i)
#pragma unroll
        for (int j = 0; j < 4; ++j) {
            short4v pk;
#pragma unroll
            for (int r = 0; r < 4; ++r) pk[r] = f2bf(acc2[j][i][r]);
            *(short4v*)&outb[(size_t)t_val[i] * DD + h * DH + j * 16 + quad * 4] = pk;
        }
}

// ---------------------------------------------------------------------------
// 4. out-proj GEMM
// ---------------------------------------------------------------------------
__global__ __launch_bounds__(256) void gemm_out(const short* __restrict__ A,
                                                const short* __restrict__ BT,
                                                const float* __restrict__ bias,
                                                float* __restrict__ Cout,
                                                int M, int N, int K) {
    __shared__ __align__(16) short As[128 * 32];
    __shared__ __align__(16) short Bs[128 * 32];
    int tid = threadIdx.x;
    int wave = tid >> 6, lane = tid & 63;
    int quad = lane >> 4, l15 = lane & 15;
    int m0 = blockIdx.x * 128, n0 = blockIdx.y * 128;
    int wr = (wave >> 1) * 64, wc = (wave & 1) * 64;

    int srow = wave * 16 + (lane >> 2);
    int scol = (lane & 3) * 8;
    const short* Ag = A + (size_t)(m0 + srow) * K + scol;
    const short* Bg = BT + (size_t)(n0 + srow) * K + scol;
    short* As0 = &As[(wave * 16) * 32];
    short* As1 = &As[(64 + wave * 16) * 32];
    short* Bs0 = &Bs[(wave * 16) * 32];
    short* Bs1 = &Bs[(64 + wave * 16) * 32];

    f32x4 acc[4][4] = {};
    for (int k0 = 0; k0 < K; k0 += 32) {
        __syncthreads();
        gload16(Ag + k0, As0);
        gload16(Ag + (size_t)64 * K + k0, As1);
        gload16(Bg + k0, Bs0);
        gload16(Bg + (size_t)64 * K + k0, Bs1);
        __syncthreads();
        bf16x8 af[4], bfr[4];
#pragma unroll
        for (int i = 0; i < 4; ++i) {
            af[i]  = *(const bf16x8*)&As[(wr + i * 16 + l15) * 32 + quad * 8];
            bfr[i] = *(const bf16x8*)&Bs[(wc + i * 16 + l15) * 32 + quad * 8];
        }
#pragma unroll
        for (int i = 0; i < 4; ++i)
#pragma unroll
            for (int j = 0; j < 4; ++j)
                acc[i][j] = mfma16(af[i], bfr[j], acc[i][j]);
    }
#pragma unroll
    for (int i = 0; i < 4; ++i)
#pragma unroll
        for (int j = 0; j < 4; ++j)
#pragma unroll
            for (int r = 0; r < 4; ++r) {
                int row = m0 + wr + i * 16 + quad * 4 + r;
                int col = n0 + wc + j * 16 + l15;
                Cout[(size_t)row * N + col] = acc[i][j][r] + bias[col];
            }
}

// ---------------------------------------------------------------------------
// Host launcher
// ---------------------------------------------------------------------------
extern "C" void kernel_launch(void* const* d_in, const int* in_sizes, int n_in,
                              void* d_out, int out_size, void* d_ws, size_t ws_size,
                              hipStream_t stream) {
    const float* state = (const float*)d_in[0];
    const float* x     = (const float*)d_in[1];
    const int*   done  = (const int*)d_in[2];
    const float* w_qkv = (const float*)d_in[3];
    const float* b_qkv = (const float*)d_in[4];
    const float* w_out = (const float*)d_in[5];
    const float* b_out = (const float*)d_in[6];

    char* ws = (char*)d_ws;
    int*   seg    = (int*)ws;                         // 8 KB
    int*   totalp = (int*)(ws + 8192);
    int*   aux    = (int*)(ws + 8256);                // 33 ints
    short* wqT    = (short*)(ws + 8448);              // 6 MB   [3072][1024]
    short* woT    = (short*)(ws + 6299904);           // 2 MB   [1024][1024]
    short* stT    = (short*)(ws + 8397056);           // 128 KB [h][e][d]
    short* qk     = (short*)(ws + 8528128);           // 8 MB   [T][2048] (Q|K)
    short* vt     = (short*)(ws + 16916736);          // 4 MB   [h][e][T]
    short* xbf_outb = (short*)(ws + 21111040);        // 4 MB   x_bf then outb

    float* new_state_out = (float*)d_out;
    float* x_out         = (float*)d_out + HH * DH * DH;

    prep_kernel<<<2129, 256, 0, stream>>>(x, w_qkv, w_out, state, done,
                                          xbf_outb, wqT, woT, stT,
                                          new_state_out, seg, totalp, aux);

    gemm_qkv<<<dim3(TT / 128, QKV_N / 128), 256, 0, stream>>>(
        xbf_outb, wqT, b_qkv, qk, vt);

    attn_mfma<<<dim3(HH, TT / 128, 2), 256, 0, stream>>>(
        qk, vt, stT, seg, totalp, aux, xbf_outb, new_state_out);

    gemm_out<<<dim3(TT / 128, DD / 128), 256, 0, stream>>>(
        xbf_outb, woT, b_out, x_out, TT, DD, DD);
}

// Round 9
// 159.376 us; speedup vs baseline: 1.0261x; 1.0261x over previous
//
#include <hip/hip_runtime.h>

#define TT 2048
#define DD 1024
#define HH 16
#define DH 64
#define QKV_N 3072
#define QKW 2048  // qk buffer width (Q cols 0..1023, K cols 1024..2047)

typedef __attribute__((ext_vector_type(8))) short bf16x8;
typedef __attribute__((ext_vector_type(4))) short short4v;
typedef __attribute__((ext_vector_type(4))) float f32x4;

__device__ inline short f2bf(float f) {
    union { float f; unsigned u; } v; v.f = f;
    unsigned r = v.u + 0x7fff + ((v.u >> 16) & 1);  // RNE
    return (short)(r >> 16);
}

__device__ inline f32x4 mfma16(bf16x8 a, bf16x8 b, f32x4 c) {
    return __builtin_amdgcn_mfma_f32_16x16x32_bf16(a, b, c, 0, 0, 0);
}

__device__ __forceinline__ void gload16(const void* g, void* l) {
    __builtin_amdgcn_global_load_lds(
        (const __attribute__((address_space(1))) unsigned int*)g,
        (__attribute__((address_space(3))) unsigned int*)l, 16, 0, 0);
}

// ---------------------------------------------------------------------------
// 1. prep: x cast, weight/state transposes, new_state init, x_out bias init,
//    scan. grid = 4177 blocks.
// ---------------------------------------------------------------------------
__device__ void transpose_tile(const float* __restrict__ in, short* __restrict__ out,
                               int R, int C, int r0, int c0, float (*tile)[65]) {
    int tid = threadIdx.x;
#pragma unroll
    for (int p = 0; p < 4; ++p) {
        int ch = tid + p * 256;
        int r = ch >> 4, c4 = (ch & 15) * 4;
        float4 v = *(const float4*)&in[(size_t)(r0 + r) * C + c0 + c4];
        tile[r][c4] = v.x; tile[r][c4 + 1] = v.y; tile[r][c4 + 2] = v.z; tile[r][c4 + 3] = v.w;
    }
    __syncthreads();
#pragma unroll
    for (int p = 0; p < 2; ++p) {
        int ch = tid + p * 256;
        int c = ch >> 3, r8 = (ch & 7) * 8;
        short tmp[8];
#pragma unroll
        for (int i = 0; i < 8; ++i) tmp[i] = f2bf(tile[r8 + i][c]);
        *(float4*)&out[(size_t)(c0 + c) * R + r0 + r8] = *(float4*)tmp;
    }
}

__global__ __launch_bounds__(256) void prep_kernel(const float* __restrict__ x,
                                                   const float* __restrict__ w_qkv,
                                                   const float* __restrict__ w_out,
                                                   const float* __restrict__ state,
                                                   const int* __restrict__ done,
                                                   const float* __restrict__ b_out,
                                                   short* __restrict__ x_bf,
                                                   short* __restrict__ wqT,
                                                   short* __restrict__ woT,
                                                   short* __restrict__ stT,
                                                   float* __restrict__ stout,
                                                   float* __restrict__ x_out,
                                                   int* __restrict__ seg,
                                                   int* __restrict__ totalp,
                                                   int* __restrict__ aux) {
    __shared__ float tile[64][65];
    __shared__ int scanbuf[2048 + 512 + 1];
    int b = blockIdx.x;
    int tid = threadIdx.x;
    if (b < 1024) {
        int i = (b * 256 + tid) * 8;
        float4 a = *(const float4*)&x[i];
        float4 c = *(const float4*)&x[i + 4];
        short tmp[8] = {f2bf(a.x), f2bf(a.y), f2bf(a.z), f2bf(a.w),
                        f2bf(c.x), f2bf(c.y), f2bf(c.z), f2bf(c.w)};
        *(float4*)&x_bf[i] = *(float4*)tmp;
    } else if (b < 1792) {
        int bb = b - 1024;
        transpose_tile(w_qkv, wqT, DD, QKV_N, (bb & 15) * 64, (bb >> 4) * 64, tile);
    } else if (b < 2048) {
        int bb = b - 1792;
        transpose_tile(w_out, woT, DD, DD, (bb & 15) * 64, (bb >> 4) * 64, tile);
    } else if (b < 2064) {
        int h = b - 2048;
        transpose_tile(state + (size_t)h * 4096, stT + (size_t)h * 4096, DH, DH, 0, 0, tile);
    } else if (b < 2128) {
        __shared__ int anyf;
        if (tid == 0) anyf = 0;
        __syncthreads();
        int acc = 0;
#pragma unroll
        for (int i = 0; i < 8; ++i) acc |= done[tid * 8 + i];
        if (acc) anyf = 1;
        __syncthreads();
        int f = ((b - 2064) * 256 + tid) * 4;
        float4 v = anyf ? make_float4(0.f, 0.f, 0.f, 0.f) : *(const float4*)&state[f];
        *(float4*)&stout[f] = v;
    } else if (b < 4176) {
        // x_out init with bias (gemm_out split-K atomicAdds on top)
        int f = ((b - 2128) * 256 + tid) * 4;
        int col = f & (DD - 1);
        *(float4*)&x_out[f] = *(const float4*)&b_out[col];
    } else {
        int* segl = scanbuf;
        int* part = scanbuf + 2048;
        int* excl = scanbuf + 2304;
        int base = tid * 8;
        int local[8];
        int run = 0;
#pragma unroll
        for (int i = 0; i < 8; ++i) { run += (done[base + i] != 0) ? 1 : 0; local[i] = run; }
        part[tid] = run;
        __syncthreads();
        if (tid < 64) {
            int p4[4];
#pragma unroll
            for (int i = 0; i < 4; ++i) p4[i] = part[tid * 4 + i];
            int s = p4[0] + p4[1] + p4[2] + p4[3];
            int v = s;
#pragma unroll
            for (int off = 1; off < 64; off <<= 1) {
                int u = __shfl_up(v, off);
                if (tid >= off) v += u;
            }
            int ex = v - s;
#pragma unroll
            for (int i = 0; i < 4; ++i) { excl[tid * 4 + i] = ex; ex += p4[i]; }
            if (tid == 63) { totalp[0] = v; scanbuf[2560] = v; }
        }
        __syncthreads();
        int off = excl[tid];
#pragma unroll
        for (int i = 0; i < 8; ++i) {
            int sv = off + local[i];
            seg[base + i] = sv;
            segl[base + i] = sv;
        }
        __syncthreads();
        if (tid < 33) {
            int target = (tid < 32) ? segl[tid * 64] : scanbuf[2560];
            int lo = 0, hi = 2047;
            while (lo < hi) { int mid = (lo + hi) >> 1; if (segl[mid] >= target) hi = mid; else lo = mid + 1; }
            aux[tid] = lo >> 6;
        }
    }
}

// ---------------------------------------------------------------------------
// 2. QKV GEMM, BK=64 as two 32-wide LDS panels (16 k-iters, half the barriers)
//    cols <2048 -> qk natural; cols >=2048 -> vt[h][e][t]
// ---------------------------------------------------------------------------
__global__ __launch_bounds__(256) void gemm_qkv(const short* __restrict__ A,
                                                const short* __restrict__ BT,
                                                const float* __restrict__ bias,
                                                short* __restrict__ qk,
                                                short* __restrict__ vt) {
    __shared__ __align__(16) short As[2][128 * 32];  // [k-half][row][32]
    __shared__ __align__(16) short Bs[2][128 * 32];
    const int K = DD;
    int tid = threadIdx.x;
    int wave = tid >> 6, lane = tid & 63;
    int quad = lane >> 4, l15 = lane & 15;
    int m0 = blockIdx.x * 128, n0 = blockIdx.y * 128;
    int wr = (wave >> 1) * 64, wc = (wave & 1) * 64;

    // staging: lane covers row wave*32 + g*16 + (lane>>2), cols (lane&3)*8 (+ks*32)
    int srow = wave * 32 + (lane >> 2);
    int scol = (lane & 3) * 8;
    const short* Ag = A + (size_t)(m0 + srow) * K + scol;
    const short* Bg = BT + (size_t)(n0 + srow) * K + scol;

    f32x4 acc[4][4] = {};
    for (int k0 = 0; k0 < K; k0 += 64) {
        __syncthreads();
#pragma unroll
        for (int g = 0; g < 2; ++g)
#pragma unroll
            for (int ks = 0; ks < 2; ++ks) {
                gload16(Ag + (size_t)g * 16 * K + k0 + ks * 32, &As[ks][(wave * 32 + g * 16) * 32]);
                gload16(Bg + (size_t)g * 16 * K + k0 + ks * 32, &Bs[ks][(wave * 32 + g * 16) * 32]);
            }
        __syncthreads();
#pragma unroll
        for (int ks = 0; ks < 2; ++ks) {
            bf16x8 af[4], bfr[4];
#pragma unroll
            for (int i = 0; i < 4; ++i) {
                af[i]  = *(const bf16x8*)&As[ks][(wr + i * 16 + l15) * 32 + quad * 8];
                bfr[i] = *(const bf16x8*)&Bs[ks][(wc + i * 16 + l15) * 32 + quad * 8];
            }
#pragma unroll
            for (int i = 0; i < 4; ++i)
#pragma unroll
                for (int j = 0; j < 4; ++j)
                    acc[i][j] = mfma16(af[i], bfr[j], acc[i][j]);
        }
    }

    if (n0 < 2048) {
#pragma unroll
        for (int i = 0; i < 4; ++i)
#pragma unroll
            for (int j = 0; j < 4; ++j)
#pragma unroll
                for (int r = 0; r < 4; ++r) {
                    int row = m0 + wr + i * 16 + quad * 4 + r;
                    int col = n0 + wc + j * 16 + l15;
                    qk[(size_t)row * QKW + col] = f2bf(acc[i][j][r] + bias[col]);
                }
    } else {
#pragma unroll
        for (int j = 0; j < 4; ++j) {
            int col = n0 + wc + j * 16 + l15;
            float bv = bias[col];
            int eg = col - 2048;
            int hh = eg >> 6, e = eg & 63;
#pragma unroll
            for (int i = 0; i < 4; ++i) {
                int tb = m0 + wr + i * 16 + quad * 4;
                short4v pk;
#pragma unroll
                for (int r = 0; r < 4; ++r) pk[r] = f2bf(acc[i][j][r] + bv);
                *(short4v*)&vt[(size_t)hh * (DH * TT) + (size_t)e * TT + tb] = pk;
            }
        }
    }
}

// ---------------------------------------------------------------------------
// 3. attention — 64-row t-tiles, s-chunks of 4 tiles (max 4-iter chain),
//    double-buffered gload16 staging, packed b64 S/epilogue stores.
//    grid (H, 32, z: 0..7 s-chunks, 8 state).
// ---------------------------------------------------------------------------
__global__ __launch_bounds__(256) void attn_mfma(const short* __restrict__ qk,
                                                 const short* __restrict__ vt,
                                                 const short* __restrict__ stT,
                                                 const int* __restrict__ seg,
                                                 const int* __restrict__ totalp,
                                                 const int* __restrict__ aux,
                                                 short* __restrict__ outb,
                                                 float* __restrict__ part,
                                                 float* __restrict__ nsout) {
    __shared__ __align__(16) short Qh[2][64 * 32];      // [d-half][t][32]
    __shared__ __align__(16) short Kh[2][2][64 * 32];   // [buf][d-half][s][32]
    __shared__ __align__(16) short Vh[2][2][64 * 32];   // [buf][s-half][e][32]
    __shared__ __align__(16) short Ss[64 * 72];         // [t][s], stride 72

    int h = blockIdx.x, tt = blockIdx.y, z = blockIdx.z;
    int t0 = tt * 64;
    int tid = threadIdx.x, wave = tid >> 6, lane = tid & 63;
    int quad = lane >> 4, l15 = lane & 15;
    int myt = wave * 16;
    const short* vbase = vt + (size_t)h * (DH * TT);

    if (z == 8) {
        // ---- state path: chunk ct = tt; atomicAdd onto prep-initialized nsout
        if (tt < aux[32]) return;
        int total = totalp[0];
        int myd = wave * 16;
        short* K0 = Kh[0][0];
        short* K1 = Kh[0][1];
        bool keep = (seg[t0 + lane] == total);
        const short* src = qk + (size_t)(t0 + lane) * QKW + 1024 + h * DH + myd;
        union { float4 f; short s[8]; } u0, u1;
        u0.f = keep ? *(const float4*)src : make_float4(0.f, 0.f, 0.f, 0.f);
        u1.f = keep ? *(const float4*)(src + 8) : make_float4(0.f, 0.f, 0.f, 0.f);
        short* dst = (lane < 32) ? &K0[lane] : &K1[lane - 32];
#pragma unroll
        for (int i = 0; i < 8; ++i) {
            dst[(myd + i) * 32] = u0.s[i];
            dst[(myd + 8 + i) * 32] = u1.s[i];
        }
        bf16x8 a0 = *(const bf16x8*)&K0[(myd + l15) * 32 + quad * 8];
        bf16x8 a1 = *(const bf16x8*)&K1[(myd + l15) * 32 + quad * 8];
        f32x4 acc2[4] = {};
#pragma unroll
        for (int j = 0; j < 4; ++j) {
            const short* vrow = vbase + (size_t)(j * 16 + l15) * TT + t0 + quad * 8;
            bf16x8 b0 = *(const bf16x8*)vrow;
            bf16x8 b1 = *(const bf16x8*)(vrow + 32);
            acc2[j] = mfma16(a0, b0, acc2[j]);
            acc2[j] = mfma16(a1, b1, acc2[j]);
        }
        float* oh = nsout + (size_t)h * 4096;
#pragma unroll
        for (int j = 0; j < 4; ++j)
#pragma unroll
            for (int r = 0; r < 4; ++r)
                atomicAdd(&oh[(myd + quad * 4 + r) * DH + j * 16 + l15], acc2[j][r]);
        return;
    }

    int st0 = aux[tt];
    int sc_lo = st0 >> 2, sc_hi = tt >> 2;
    if (z < sc_lo || z > sc_hi) return;
    bool direct = (sc_lo == sc_hi);
    int st_lo = (st0 > z * 4) ? st0 : z * 4;
    int st_hi = (tt < z * 4 + 3) ? tt : z * 4 + 3;

    int sr = lane >> 2;          // staging row within 16
    int ch = lane & 3;           // staging col chunk
    const short* kg = qk + 1024 + h * DH;

    // stage Q (wave-private 16 rows) + first K/V tile into buf 0
    {
#pragma unroll
        for (int h2 = 0; h2 < 2; ++h2)
            gload16(qk + (size_t)(t0 + myt + sr) * QKW + h * DH + h2 * 32 + ch * 8,
                    &Qh[h2][myt * 32]);
        int s0 = st_lo * 64;
        gload16(kg + (size_t)(s0 + myt + sr) * QKW + ch * 8,      &Kh[0][0][myt * 32]);
        gload16(kg + (size_t)(s0 + myt + sr) * QKW + 32 + ch * 8, &Kh[0][1][myt * 32]);
        gload16(vbase + (size_t)(myt + sr) * TT + s0 + ch * 8,    &Vh[0][0][myt * 32]);
        gload16(vbase + (size_t)(myt + sr) * TT + s0 + 32 + ch * 8, &Vh[0][1][myt * 32]);
    }
    __syncthreads();

    bf16x8 af[2];
#pragma unroll
    for (int h2 = 0; h2 < 2; ++h2)
        af[h2] = *(const bf16x8*)&Qh[h2][(myt + l15) * 32 + quad * 8];

    int t_val = t0 + myt + l15;
    int seg_lane = seg[t_val];

    f32x4 acc2[4] = {};  // out^T: e=j*16+quad*4+r, t=myt+l15
    if (z == sc_lo && seg[t0] == 0) {
        const short* sb = stT + (size_t)h * 4096;  // [e][d]
#pragma unroll
        for (int j = 0; j < 4; ++j)
#pragma unroll
            for (int h2 = 0; h2 < 2; ++h2) {
                bf16x8 a = *(const bf16x8*)(sb + (j * 16 + l15) * 64 + h2 * 32 + quad * 8);
                acc2[j] = mfma16(a, af[h2], acc2[j]);
            }
        if (seg_lane != 0) {
#pragma unroll
            for (int j = 0; j < 4; ++j)
#pragma unroll
                for (int r = 0; r < 4; ++r) acc2[j][r] = 0.f;
        }
    }

    int p = 0;
    for (int st = st_lo; st <= st_hi; ++st, p ^= 1) {
        if (st != st_lo) __syncthreads();
        if (st + 1 <= st_hi) {
            int s1 = (st + 1) * 64;
            gload16(kg + (size_t)(s1 + myt + sr) * QKW + ch * 8,        &Kh[p ^ 1][0][myt * 32]);
            gload16(kg + (size_t)(s1 + myt + sr) * QKW + 32 + ch * 8,   &Kh[p ^ 1][1][myt * 32]);
            gload16(vbase + (size_t)(myt + sr) * TT + s1 + ch * 8,      &Vh[p ^ 1][0][myt * 32]);
            gload16(vbase + (size_t)(myt + sr) * TT + s1 + 32 + ch * 8, &Vh[p ^ 1][1][myt * 32]);
        }
        int s0 = st * 64;

        // S^T = K Q^T : D[s][t], s=j*16+quad*4+r, t=myt+l15
        f32x4 sacc[4] = {};
#pragma unroll
        for (int j = 0; j < 4; ++j)
#pragma unroll
            for (int h2 = 0; h2 < 2; ++h2) {
                bf16x8 kb = *(const bf16x8*)&Kh[p][h2][(j * 16 + l15) * 32 + quad * 8];
                sacc[j] = mfma16(kb, af[h2], sacc[j]);
            }
        // mask + packed b64 stores into Ss[t][s] (wave-private rows)
        int4 seg4[4];
#pragma unroll
        for (int j = 0; j < 4; ++j)
            seg4[j] = *(const int4*)&seg[s0 + j * 16 + quad * 4];
#pragma unroll
        for (int j = 0; j < 4; ++j) {
            short4v pk;
#pragma unroll
            for (int r = 0; r < 4; ++r) {
                int s_val = s0 + j * 16 + quad * 4 + r;
                int sv = (r == 0) ? seg4[j].x : (r == 1) ? seg4[j].y : (r == 2) ? seg4[j].z : seg4[j].w;
                bool ok = (sv == seg_lane) && (s_val <= t_val);
                pk[r] = ok ? f2bf(sacc[j][r]) : (short)0;
            }
            *(short4v*)&Ss[(myt + l15) * 72 + j * 16 + quad * 4] = pk;
        }
        // out^T += V^T S^T
        bf16x8 sf[2];
#pragma unroll
        for (int h2 = 0; h2 < 2; ++h2)
            sf[h2] = *(const bf16x8*)&Ss[(myt + l15) * 72 + h2 * 32 + quad * 8];
#pragma unroll
        for (int j = 0; j < 4; ++j)
#pragma unroll
            for (int h2 = 0; h2 < 2; ++h2) {
                bf16x8 vb = *(const bf16x8*)&Vh[p][h2][(j * 16 + l15) * 32 + quad * 8];
                acc2[j] = mfma16(vb, sf[h2], acc2[j]);
            }
    }

    if (direct) {
#pragma unroll
        for (int j = 0; j < 4; ++j) {
            short4v pk;
#pragma unroll
            for (int r = 0; r < 4; ++r) pk[r] = f2bf(acc2[j][r]);
            *(short4v*)&outb[(size_t)t_val * DD + h * DH + j * 16 + quad * 4] = pk;
        }
    } else {
        float* pb = part + ((size_t)((h * 32 + tt) * 8 + z)) * 4096;  // [64][64]
#pragma unroll
        for (int j = 0; j < 4; ++j)
            *(f32x4*)&pb[(myt + l15) * 64 + j * 16 + quad * 4] = acc2[j];
    }
}

// ---------------------------------------------------------------------------
// 4. reduce multi-chunk partials -> outb bf16
// ---------------------------------------------------------------------------
__global__ __launch_bounds__(256) void attn_reduce(const float* __restrict__ part,
                                                   const int* __restrict__ aux,
                                                   short* __restrict__ outb) {
    int h = blockIdx.x, tt = blockIdx.y;
    int sc_lo = aux[tt] >> 2, sc_hi = tt >> 2;
    if (sc_lo == sc_hi) return;
    int t0 = tt * 64;
    int tid = threadIdx.x;
    const float* pb = part + ((size_t)(h * 32 + tt) * 8) * 4096;
#pragma unroll
    for (int p = 0; p < 4; ++p) {
        int idx = p * 256 + tid;        // 0..1023 over [64 rows][16 f4-chunks]
        int row = idx >> 4, c4 = (idx & 15) * 4;
        float4 acc = make_float4(0.f, 0.f, 0.f, 0.f);
        for (int sc = sc_lo; sc <= sc_hi; ++sc) {
            float4 v = *(const float4*)&pb[(size_t)sc * 4096 + row * 64 + c4];
            acc.x += v.x; acc.y += v.y; acc.z += v.z; acc.w += v.w;
        }
        short4v pk;
        pk[0] = f2bf(acc.x); pk[1] = f2bf(acc.y); pk[2] = f2bf(acc.z); pk[3] = f2bf(acc.w);
        *(short4v*)&outb[(size_t)(t0 + row) * DD + h * DH + c4] = pk;
    }
}

// ---------------------------------------------------------------------------
// 5. out-proj GEMM, split-K=2 (grid 16x8x2 = 256 balanced blocks), atomicAdd
//    onto bias-initialized x_out.
// ---------------------------------------------------------------------------
__global__ __launch_bounds__(256) void gemm_out(const short* __restrict__ A,
                                                const short* __restrict__ BT,
                                                float* __restrict__ Cout,
                                                int M, int N, int K) {
    __shared__ __align__(16) short As[128 * 32];
    __shared__ __align__(16) short Bs[128 * 32];
    int tid = threadIdx.x;
    int wave = tid >> 6, lane = tid & 63;
    int quad = lane >> 4, l15 = lane & 15;
    int m0 = blockIdx.x * 128, n0 = blockIdx.y * 128;
    int kb0 = blockIdx.z * (K / 2), kb1 = kb0 + K / 2;
    int wr = (wave >> 1) * 64, wc = (wave & 1) * 64;

    int srow = wave * 16 + (lane >> 2);
    int scol = (lane & 3) * 8;
    const short* Ag = A + (size_t)(m0 + srow) * K + scol;
    const short* Bg = BT + (size_t)(n0 + srow) * K + scol;
    short* As0 = &As[(wave * 16) * 32];
    short* As1 = &As[(64 + wave * 16) * 32];
    short* Bs0 = &Bs[(wave * 16) * 32];
    short* Bs1 = &Bs[(64 + wave * 16) * 32];

    f32x4 acc[4][4] = {};
    for (int k0 = kb0; k0 < kb1; k0 += 32) {
        __syncthreads();
        gload16(Ag + k0, As0);
        gload16(Ag + (size_t)64 * K + k0, As1);
        gload16(Bg + k0, Bs0);
        gload16(Bg + (size_t)64 * K + k0, Bs1);
        __syncthreads();
        bf16x8 af[4], bfr[4];
#pragma unroll
        for (int i = 0; i < 4; ++i) {
            af[i]  = *(const bf16x8*)&As[(wr + i * 16 + l15) * 32 + quad * 8];
            bfr[i] = *(const bf16x8*)&Bs[(wc + i * 16 + l15) * 32 + quad * 8];
        }
#pragma unroll
        for (int i = 0; i < 4; ++i)
#pragma unroll
            for (int j = 0; j < 4; ++j)
                acc[i][j] = mfma16(af[i], bfr[j], acc[i][j]);
    }
#pragma unroll
    for (int i = 0; i < 4; ++i)
#pragma unroll
        for (int j = 0; j < 4; ++j)
#pragma unroll
            for (int r = 0; r < 4; ++r) {
                int row = m0 + wr + i * 16 + quad * 4 + r;
                int col = n0 + wc + j * 16 + l15;
                atomicAdd(&Cout[(size_t)row * N + col], acc[i][j][r]);
            }
}

// ---------------------------------------------------------------------------
// Host launcher
// ---------------------------------------------------------------------------
extern "C" void kernel_launch(void* const* d_in, const int* in_sizes, int n_in,
                              void* d_out, int out_size, void* d_ws, size_t ws_size,
                              hipStream_t stream) {
    const float* state = (const float*)d_in[0];
    const float* x     = (const float*)d_in[1];
    const int*   done  = (const int*)d_in[2];
    const float* w_qkv = (const float*)d_in[3];
    const float* b_qkv = (const float*)d_in[4];
    const float* w_out = (const float*)d_in[5];
    const float* b_out = (const float*)d_in[6];

    char* ws = (char*)d_ws;
    int*   seg    = (int*)ws;                         // 8 KB
    int*   totalp = (int*)(ws + 8192);
    int*   aux    = (int*)(ws + 8256);                // 33 ints
    short* wqT    = (short*)(ws + 8448);              // 6 MB   [3072][1024]
    short* woT    = (short*)(ws + 6299904);           // 2 MB   [1024][1024]
    short* stT    = (short*)(ws + 8397056);           // 128 KB [h][e][d]
    short* qk     = (short*)(ws + 8528128);           // 8 MB   [T][2048] (Q|K)
    short* vt     = (short*)(ws + 16916736);          // 4 MB   [h][e][T]
    short* xbf_outb = (short*)(ws + 21111040);        // 4 MB   x_bf then outb
    float* part   = (float*)(ws + 25305344);          // 64 MB  [h][tt][sc][64][64]

    float* new_state_out = (float*)d_out;
    float* x_out         = (float*)d_out + HH * DH * DH;

    prep_kernel<<<4177, 256, 0, stream>>>(x, w_qkv, w_out, state, done, b_out,
                                          xbf_outb, wqT, woT, stT,
                                          new_state_out, x_out, seg, totalp, aux);

    gemm_qkv<<<dim3(TT / 128, QKV_N / 128), 256, 0, stream>>>(
        xbf_outb, wqT, b_qkv, qk, vt);

    attn_mfma<<<dim3(HH, TT / 64, 9), 256, 0, stream>>>(
        qk, vt, stT, seg, totalp, aux, xbf_outb, part, new_state_out);

    attn_reduce<<<dim3(HH, TT / 64), 256, 0, stream>>>(part, aux, xbf_outb);

    gemm_out<<<dim3(TT / 128, DD / 128, 2), 256, 0, stream>>>(
        xbf_outb, woT, x_out, TT, DD, DD);
}